// Round 2
// baseline (1989.164 us; speedup 1.0000x reference)
//
#include <hip/hip_runtime.h>

static constexpr int HID  = 4096;  // hidden size
static constexpr int SEQL = 40;
static constexpr int OUTN = 128;
static constexpr int NBLK = 256;   // 256 blocks x 1024 thr: 1 block/CU co-resident

// ---------- fp32 -> bf16 (RNE) ----------
__device__ __forceinline__ unsigned f2bf(float f) {
    unsigned u = __float_as_uint(f);
    return (u + 0x7fffu + ((u >> 16) & 1u)) >> 16;
}
__device__ __forceinline__ unsigned pack2(float lo, float hi) {
    return f2bf(lo) | (f2bf(hi) << 16);
}
__device__ __forceinline__ uint4 pack8(float4 a, float4 b) {
    uint4 r;
    r.x = pack2(a.x, a.y);
    r.y = pack2(a.z, a.w);
    r.z = pack2(b.x, b.y);
    r.w = pack2(b.z, b.w);
    return r;
}

// Zero h0|h1|ctr region (contiguous dwords at start of ws; harness poisons ws).
__global__ void init_ws_kernel(unsigned* __restrict__ p, int n) {
    int i = blockIdx.x * blockDim.x + threadIdx.x;
    if (i < n) p[i] = 0u;
}

// ---------- helpers ----------
__device__ __forceinline__ float bflo(unsigned u) { return __uint_as_float(u << 16); }
__device__ __forceinline__ float bfhi(unsigned u) { return __uint_as_float(u & 0xffff0000u); }

__device__ __forceinline__ float dot8_bf(uint4 w, float4 ha, float4 hb, float acc) {
    acc = fmaf(bflo(w.x), ha.x, acc);
    acc = fmaf(bfhi(w.x), ha.y, acc);
    acc = fmaf(bflo(w.y), ha.z, acc);
    acc = fmaf(bfhi(w.y), ha.w, acc);
    acc = fmaf(bflo(w.z), hb.x, acc);
    acc = fmaf(bfhi(w.z), hb.y, acc);
    acc = fmaf(bflo(w.w), hb.z, acc);
    acc = fmaf(bfhi(w.w), hb.w, acc);
    return acc;
}

__device__ __forceinline__ float dot8_f32(float4 wa, float4 wb, float4 ha, float4 hb, float acc) {
    acc = fmaf(wa.x, ha.x, acc);
    acc = fmaf(wa.y, ha.y, acc);
    acc = fmaf(wa.z, ha.z, acc);
    acc = fmaf(wa.w, ha.w, acc);
    acc = fmaf(wb.x, hb.x, acc);
    acc = fmaf(wb.y, hb.y, acc);
    acc = fmaf(wb.z, hb.z, acc);
    acc = fmaf(wb.w, hb.w, acc);
    return acc;
}

__device__ __forceinline__ float sigm(float x) { return 1.0f / (1.0f + expf(-x)); }

// Stage the 16KB h vector into LDS: one 16B L2-bypassing (sc0 sc1 ->
// MALL-coherent) load per thread. Never reads a stale XCD-L2 line.
__device__ __forceinline__ void stage_h(float* __restrict__ hsh,
                                        const float* __restrict__ hsrc) {
    int base = threadIdx.x * 4;
    const float* p = hsrc + base;
    float4 v;
    asm volatile("global_load_dwordx4 %0, %1, off sc0 sc1\n\t"
                 "s_waitcnt vmcnt(0)"
                 : "=v"(v) : "v"(p) : "memory");
    *(float4*)(hsh + base) = v;
}

// ---------- persistent LSTM with FULLY ON-CHIP WEIGHTS ----------
// 256 blocks x 1024 threads = 4096 waves = one wave per hidden unit j.
// Key fact: each CU re-reads the SAME 512 KB of bf16 weights all 40 steps,
// and 512 KB is exactly one CU's on-chip capacity:
//   regs: 16 waves x 128 VGPR x 64 lanes x 4 B = 512 KB total file
//   LDS : 160 KB
// Partition per wave (32 KB of weights):
//   gate i (8 KB) + gate f (8 KB) + gate g chunks 0..6 (7 KB) -> 92 VGPRs/lane
//   gate o (8 KB) + gate g chunk 7 (1 KB)                     -> 9 KB LDS/wave
// LDS total: h 16 KB + gate-o 128 KB + gate-g7 16 KB = 160 KB exactly.
// Weights are loaded ONCE from the fp32 input (converted to bf16 in-register,
// same RNE as before -> identical numerics), so steps 1..39 have ZERO weight
// traffic; per-step global traffic is just the 16 KB h exchange + barrier.
__global__ void __launch_bounds__(1024, 4)
lstm_kernel(const float* __restrict__ x,
            const float* __restrict__ w_ih,
            const float* __restrict__ b_ih,
            const float* __restrict__ b_hh,
            const float* __restrict__ w_hh,
            const float* __restrict__ dense_w,
            const float* __restrict__ dense_b,
            float* __restrict__ h0,
            float* __restrict__ h1,
            unsigned* __restrict__ ctr,
            float* __restrict__ out) {
    extern __shared__ float smem[];
    float* hsh   = smem;                          // 4096 f32 (16 KB)
    uint4* ldsO  = (uint4*)(smem + HID);          // 8192 uint4 (128 KB)
    uint4* ldsG7 = (uint4*)(smem + HID + 32768);  // 1024 uint4 (16 KB)

    const int lane = threadIdx.x & 63;
    const int wv   = threadIdx.x >> 6;                 // wave in block, 0..15
    const int j    = (blockIdx.x << 4) | wv;           // hidden unit, 0..4095

    float wih0 = w_ih[0 * HID + j], bb0 = b_ih[0 * HID + j] + b_hh[0 * HID + j];
    float wih1 = w_ih[1 * HID + j], bb1 = b_ih[1 * HID + j] + b_hh[1 * HID + j];
    float wih2 = w_ih[2 * HID + j], bb2 = b_ih[2 * HID + j] + b_hh[2 * HID + j];
    float wih3 = w_ih[3 * HID + j], bb3 = b_ih[3 * HID + j] + b_hh[3 * HID + j];

    const float4* qi = (const float4*)(w_hh + (size_t)(0 * HID + j) * HID);
    const float4* qf = (const float4*)(w_hh + (size_t)(1 * HID + j) * HID);
    const float4* qg = (const float4*)(w_hh + (size_t)(2 * HID + j) * HID);
    const float4* qo = (const float4*)(w_hh + (size_t)(3 * HID + j) * HID);

    // ---- prologue: load fp32 weights once, pack bf16 into regs + LDS ----
    uint4 wi[8], wf[8], wg[7];
#pragma unroll
    for (int it = 0; it < 8; ++it) {
        int i0 = it * 128 + lane * 2;
        wi[it] = pack8(qi[i0], qi[i0 + 1]);
        wf[it] = pack8(qf[i0], qf[i0 + 1]);
        if (it < 7) wg[it] = pack8(qg[i0], qg[i0 + 1]);
        ldsO[wv * 512 + it * 64 + lane] = pack8(qo[i0], qo[i0 + 1]);
    }
    {
        int i0 = 7 * 128 + lane * 2;
        ldsG7[wv * 64 + lane] = pack8(qg[i0], qg[i0 + 1]);
    }
    // No barrier needed for weight LDS: each wave writes/reads only its own
    // region; the per-step __syncthreads covers the h region.

    float c = 0.0f;

    for (int t = 0; t < SEQL; ++t) {
        const float* hr = (t & 1) ? h1 : h0;   // t=0 reads h0 (zeros from init)
        float*       hw = (t & 1) ? h0 : h1;

        stage_h(hsh, hr);
        __syncthreads();

        const float4* hv = (const float4*)hsh;
        float xt = x[t];
        float acc0 = 0.f, acc1 = 0.f, acc2 = 0.f, acc3 = 0.f;

#pragma unroll
        for (int it = 0; it < 8; ++it) {
            float4 ha = hv[it * 128 + lane * 2];
            float4 hb = hv[it * 128 + lane * 2 + 1];
            uint4 ow = ldsO[wv * 512 + it * 64 + lane];
            uint4 cg = (it < 7) ? wg[it] : ldsG7[wv * 64 + lane];
            acc0 = dot8_bf(wi[it], ha, hb, acc0);
            acc1 = dot8_bf(wf[it], ha, hb, acc1);
            acc2 = dot8_bf(cg,     ha, hb, acc2);
            acc3 = dot8_bf(ow,     ha, hb, acc3);
        }

#pragma unroll
        for (int off = 32; off; off >>= 1) {
            acc0 += __shfl_xor(acc0, off, 64);
            acc1 += __shfl_xor(acc1, off, 64);
            acc2 += __shfl_xor(acc2, off, 64);
            acc3 += __shfl_xor(acc3, off, 64);
        }
        float gi = acc0 + wih0 * xt + bb0;
        float gf = acc1 + wih1 * xt + bb1;
        float gg = acc2 + wih2 * xt + bb2;
        float go = acc3 + wih3 * xt + bb3;
        c = sigm(gf) * c + sigm(gi) * tanhf(gg);
        float hn = sigm(go) * tanhf(c);
        if (lane == 0)
            __hip_atomic_store(hw + j, hn, __ATOMIC_RELAXED, __HIP_MEMORY_SCOPE_AGENT);

        // ---- hand-rolled device barrier for step t ----
        // __syncthreads drains each wave's h-store (vmcnt(0) before s_barrier),
        // so one RELEASE add per block suffices; readers re-fetch h via
        // MALL-direct loads, so no acquire/L2-invalidate is needed.
        __syncthreads();
        if (threadIdx.x == 0) {
            __hip_atomic_fetch_add(ctr + t, 1u, __ATOMIC_RELEASE, __HIP_MEMORY_SCOPE_AGENT);
            while (__hip_atomic_load(ctr + t, __ATOMIC_RELAXED, __HIP_MEMORY_SCOPE_AGENT)
                   < (unsigned)NBLK)
                __builtin_amdgcn_s_sleep(2);
        }
        __syncthreads();
    }

    // Final h is in h0 (t=39 odd wrote hw=h0). Dense epilogue on blocks 0-7.
    if (blockIdx.x < OUTN / 16) {
        stage_h(hsh, h0);
        __syncthreads();
        const float4* hv  = (const float4*)hsh;
        const float4* dwr = (const float4*)(dense_w + (size_t)j * HID);
        float acc = 0.f;
#pragma unroll
        for (int it = 0; it < 8; ++it) {
            int i0 = it * 128 + lane * 2;
            acc = dot8_f32(dwr[i0], dwr[i0 + 1], hv[i0], hv[i0 + 1], acc);
        }
#pragma unroll
        for (int off = 32; off; off >>= 1) acc += __shfl_xor(acc, off, 64);
        if (lane == 0) out[j] = acc + dense_b[j];
    }
}

extern "C" void kernel_launch(void* const* d_in, const int* in_sizes, int n_in,
                              void* d_out, int out_size, void* d_ws, size_t ws_size,
                              hipStream_t stream) {
    const float* x       = (const float*)d_in[0];
    const float* w_ih    = (const float*)d_in[1];
    const float* w_hh    = (const float*)d_in[2];
    const float* b_ih    = (const float*)d_in[3];
    const float* b_hh    = (const float*)d_in[4];
    const float* dense_w = (const float*)d_in[5];
    const float* dense_b = (const float*)d_in[6];
    float* out = (float*)d_out;

    // ws layout: h0[4096] f32 | h1[4096] f32 | ctr[64] u32
    float*    h0  = (float*)d_ws;
    float*    h1  = h0 + HID;
    unsigned* ctr = (unsigned*)(h1 + HID);

    // Zero h0|h1|ctr (contiguous 2*HID + 64 dwords; harness poisons ws).
    int nz = 2 * HID + 64;
    init_ws_kernel<<<(nz + 1023) / 1024, 1024, 0, stream>>>((unsigned*)d_ws, nz);

    void* fn = (void*)lstm_kernel;
    static int smem_attr_set = 0;
    if (!smem_attr_set) {
        hipFuncSetAttribute(fn, hipFuncAttributeMaxDynamicSharedMemorySize,
                            160 * 1024);
        smem_attr_set = 1;
    }

    void* args[] = {(void*)&x, (void*)&w_ih, (void*)&b_ih, (void*)&b_hh,
                    (void*)&w_hh, (void*)&dense_w, (void*)&dense_b,
                    (void*)&h0, (void*)&h1, (void*)&ctr, (void*)&out};
    hipLaunchCooperativeKernel(fn, dim3(NBLK), dim3(1024), args,
                               160 * 1024, stream);
}

// Round 3
// 1570.845 us; speedup vs baseline: 1.2663x; 1.2663x over previous
//
#include <hip/hip_runtime.h>

static constexpr int HID  = 4096;  // hidden size
static constexpr int SEQL = 40;
static constexpr int OUTN = 128;
static constexpr int NBLK = 256;   // 256 blocks x 1024 thr: 1 block/CU co-resident

// ---------- fp32 -> bf16 (RNE) ----------
__device__ __forceinline__ unsigned f2bf(float f) {
    unsigned u = __float_as_uint(f);
    return (u + 0x7fffu + ((u >> 16) & 1u)) >> 16;
}
__device__ __forceinline__ unsigned pack2(float lo, float hi) {
    return f2bf(lo) | (f2bf(hi) << 16);
}
__device__ __forceinline__ uint4 pack8(float4 a, float4 b) {
    uint4 r;
    r.x = pack2(a.x, a.y);
    r.y = pack2(a.z, a.w);
    r.z = pack2(b.x, b.y);
    r.w = pack2(b.z, b.w);
    return r;
}

// Convert ONLY the gate-o block (rows 3H..4H of w_hh) to bf16: 32 MB output.
__global__ void convert_o_kernel(const float4* __restrict__ w,
                                 uint4* __restrict__ o, int n8) {
    int stride = gridDim.x * blockDim.x;
    for (int i = blockIdx.x * blockDim.x + threadIdx.x; i < n8; i += stride) {
        float4 a = w[2 * i];
        float4 b = w[2 * i + 1];
        o[i] = pack8(a, b);
    }
}

// Zero h0|h1|ctr region (contiguous dwords at start of ws; harness poisons ws).
__global__ void init_ws_kernel(unsigned* __restrict__ p, int n) {
    int i = blockIdx.x * blockDim.x + threadIdx.x;
    if (i < n) p[i] = 0u;
}

// ---------- helpers ----------
__device__ __forceinline__ float bflo(unsigned u) { return __uint_as_float(u << 16); }
__device__ __forceinline__ float bfhi(unsigned u) { return __uint_as_float(u & 0xffff0000u); }

__device__ __forceinline__ float dot8_bf(uint4 w, float4 ha, float4 hb, float acc) {
    acc = fmaf(bflo(w.x), ha.x, acc);
    acc = fmaf(bfhi(w.x), ha.y, acc);
    acc = fmaf(bflo(w.y), ha.z, acc);
    acc = fmaf(bfhi(w.y), ha.w, acc);
    acc = fmaf(bflo(w.z), hb.x, acc);
    acc = fmaf(bfhi(w.z), hb.y, acc);
    acc = fmaf(bflo(w.w), hb.z, acc);
    acc = fmaf(bfhi(w.w), hb.w, acc);
    return acc;
}

__device__ __forceinline__ float dot8_f32(float4 wa, float4 wb, float4 ha, float4 hb, float acc) {
    acc = fmaf(wa.x, ha.x, acc);
    acc = fmaf(wa.y, ha.y, acc);
    acc = fmaf(wa.z, ha.z, acc);
    acc = fmaf(wa.w, ha.w, acc);
    acc = fmaf(wb.x, hb.x, acc);
    acc = fmaf(wb.y, hb.y, acc);
    acc = fmaf(wb.z, hb.z, acc);
    acc = fmaf(wb.w, hb.w, acc);
    return acc;
}

__device__ __forceinline__ float sigm(float x) { return 1.0f / (1.0f + expf(-x)); }

// Stage the 16KB h vector into LDS: one 16B L2-bypassing (sc0 sc1 ->
// MALL-coherent) load per thread. Never reads a stale XCD-L2 line.
__device__ __forceinline__ void stage_h(float* __restrict__ hsh,
                                        const float* __restrict__ hsrc) {
    int base = threadIdx.x * 4;
    const float* p = hsrc + base;
    float4 v;
    asm volatile("global_load_dwordx4 %0, %1, off sc0 sc1\n\t"
                 "s_waitcnt vmcnt(0)"
                 : "=v"(v) : "v"(p) : "memory");
    *(float4*)(hsh + base) = v;
}

// ---------- persistent LSTM, weights on-chip (regs + LDS) + L2 stream ----------
// 256 blocks x 1024 threads = 4096 waves = one wave per hidden unit j.
// Per-wave weight partition (32 chunks of 1KB bf16 per unit):
//   gate i (8 chunks) + gate f (8 chunks)      -> 64 VGPRs/lane, persistent
//   gate g (8 chunks) + gate o chunk 0         -> 9 KB LDS/wave
//   gate o chunks 1..7                         -> streamed bf16, depth-2 prefetch
// LDS: h 16 KB + gateG 128 KB + gateO0 16 KB = 160 KB exactly.
// Streamed footprint: 7 KB/wave * 16 = 112 KB/CU -> 3.6 MB/XCD < 4 MB L2,
// so steps 1..39 read it at L2 speed; HBM sees only the prologue + h exchange.
//
// amdgpu_waves_per_eu(4,4): the unambiguous backend attribute. R0-R2 showed
// __launch_bounds__(1024,4) left the VGPR budget at 64 (spill disaster when
// weights were made persistent); [4,4] waves/EU forces the 128-reg budget,
// which is also the hard floor to launch a 16-wave block at 1 block/CU.
template <bool STRB>
__global__ void
__attribute__((amdgpu_flat_work_group_size(1024, 1024), amdgpu_waves_per_eu(4, 4)))
lstm_kernel(const float* __restrict__ x,
            const float* __restrict__ w_ih,
            const float* __restrict__ b_ih,
            const float* __restrict__ b_hh,
            const float* __restrict__ w_hh,
            const unsigned short* __restrict__ obf,
            const float* __restrict__ dense_w,
            const float* __restrict__ dense_b,
            float* __restrict__ h0,
            float* __restrict__ h1,
            unsigned* __restrict__ ctr,
            float* __restrict__ out) {
    extern __shared__ float smem[];
    float* hsh   = smem;                          // [0,16K): 4096 f32
    uint4* ldsG  = (uint4*)(smem + HID);          // [16K,144K): 16w x 512 uint4
    uint4* ldsO0 = (uint4*)(smem + HID + 32768);  // [144K,160K): 16w x 64 uint4

    const int lane = threadIdx.x & 63;
    const int wv   = threadIdx.x >> 6;                 // wave in block, 0..15
    const int j    = (blockIdx.x << 4) | wv;           // hidden unit, 0..4095

    float wih0 = w_ih[0 * HID + j], bb0 = b_ih[0 * HID + j] + b_hh[0 * HID + j];
    float wih1 = w_ih[1 * HID + j], bb1 = b_ih[1 * HID + j] + b_hh[1 * HID + j];
    float wih2 = w_ih[2 * HID + j], bb2 = b_ih[2 * HID + j] + b_hh[2 * HID + j];
    float wih3 = w_ih[3 * HID + j], bb3 = b_ih[3 * HID + j] + b_hh[3 * HID + j];

    const float4* qi = (const float4*)(w_hh + (size_t)(0 * HID + j) * HID);
    const float4* qf = (const float4*)(w_hh + (size_t)(1 * HID + j) * HID);
    const float4* qg = (const float4*)(w_hh + (size_t)(2 * HID + j) * HID);
    const float4* qo = (const float4*)(w_hh + (size_t)(3 * HID + j) * HID);
    const uint4*  po = (const uint4*)(obf + (size_t)j * HID);

    // ---- prologue: load fp32 weights once, pack bf16 into regs + LDS ----
    uint4 wi[8], wf[8];
#pragma unroll
    for (int it = 0; it < 8; ++it) {
        int i0 = it * 128 + lane * 2;
        wi[it] = pack8(qi[i0], qi[i0 + 1]);
        wf[it] = pack8(qf[i0], qf[i0 + 1]);
        ldsG[wv * 512 + it * 64 + lane] = pack8(qg[i0], qg[i0 + 1]);
    }
    ldsO0[wv * 64 + lane] = pack8(qo[lane * 2], qo[lane * 2 + 1]);
    // No barrier needed for weight LDS: each wave writes/reads only its own
    // region; the per-step __syncthreads covers the h region.

    float c = 0.0f;

    for (int t = 0; t < SEQL; ++t) {
        const float* hr = (t & 1) ? h1 : h0;   // t=0 reads h0 (zeros from init)
        float*       hw = (t & 1) ? h0 : h1;

        // Issue the first streamed gate-o chunk BEFORE the h broadcast: its
        // L2 latency hides under stage_h's MALL-latency vmcnt(0) drain.
        uint4 onxt;
        if constexpr (STRB) {
            onxt = po[64 + lane];
        } else {
            int i0 = 128 + lane * 2;
            onxt = pack8(qo[i0], qo[i0 + 1]);
        }

        stage_h(hsh, hr);
        __syncthreads();

        const float4* hv = (const float4*)hsh;
        float xt = x[t];
        float acc0 = 0.f, acc1 = 0.f, acc2 = 0.f, acc3 = 0.f;

#pragma unroll
        for (int it = 0; it < 8; ++it) {
            float4 ha = hv[it * 128 + lane * 2];
            float4 hb = hv[it * 128 + lane * 2 + 1];
            uint4 cg = ldsG[wv * 512 + it * 64 + lane];
            uint4 ow = (it == 0) ? ldsO0[wv * 64 + lane] : onxt;
            if (it > 0 && it < 7) {  // depth-2 prefetch of next streamed chunk
                if constexpr (STRB) {
                    onxt = po[(it + 1) * 64 + lane];
                } else {
                    int i2 = (it + 1) * 128 + lane * 2;
                    onxt = pack8(qo[i2], qo[i2 + 1]);
                }
            }
            acc0 = dot8_bf(wi[it], ha, hb, acc0);
            acc1 = dot8_bf(wf[it], ha, hb, acc1);
            acc2 = dot8_bf(cg,     ha, hb, acc2);
            acc3 = dot8_bf(ow,     ha, hb, acc3);
        }

#pragma unroll
        for (int off = 32; off; off >>= 1) {
            acc0 += __shfl_xor(acc0, off, 64);
            acc1 += __shfl_xor(acc1, off, 64);
            acc2 += __shfl_xor(acc2, off, 64);
            acc3 += __shfl_xor(acc3, off, 64);
        }
        float gi = acc0 + wih0 * xt + bb0;
        float gf = acc1 + wih1 * xt + bb1;
        float gg = acc2 + wih2 * xt + bb2;
        float go = acc3 + wih3 * xt + bb3;
        c = sigm(gf) * c + sigm(gi) * tanhf(gg);
        float hn = sigm(go) * tanhf(c);
        if (lane == 0)
            __hip_atomic_store(hw + j, hn, __ATOMIC_RELAXED, __HIP_MEMORY_SCOPE_AGENT);

        // ---- hand-rolled device barrier for step t ----
        __syncthreads();
        if (threadIdx.x == 0) {
            __hip_atomic_fetch_add(ctr + t, 1u, __ATOMIC_RELEASE, __HIP_MEMORY_SCOPE_AGENT);
            while (__hip_atomic_load(ctr + t, __ATOMIC_RELAXED, __HIP_MEMORY_SCOPE_AGENT)
                   < (unsigned)NBLK)
                __builtin_amdgcn_s_sleep(2);
        }
        __syncthreads();
    }

    // Final h is in h0 (t=39 odd wrote hw=h0). Dense epilogue on blocks 0-7.
    if (blockIdx.x < OUTN / 16) {
        stage_h(hsh, h0);
        __syncthreads();
        const float4* hv  = (const float4*)hsh;
        const float4* dwr = (const float4*)(dense_w + (size_t)j * HID);
        float acc = 0.f;
#pragma unroll
        for (int it = 0; it < 8; ++it) {
            int i0 = it * 128 + lane * 2;
            acc = dot8_f32(dwr[i0], dwr[i0 + 1], hv[i0], hv[i0 + 1], acc);
        }
#pragma unroll
        for (int off = 32; off; off >>= 1) acc += __shfl_xor(acc, off, 64);
        if (lane == 0) out[j] = acc + dense_b[j];
    }
}

extern "C" void kernel_launch(void* const* d_in, const int* in_sizes, int n_in,
                              void* d_out, int out_size, void* d_ws, size_t ws_size,
                              hipStream_t stream) {
    const float* x       = (const float*)d_in[0];
    const float* w_ih    = (const float*)d_in[1];
    const float* w_hh    = (const float*)d_in[2];
    const float* b_ih    = (const float*)d_in[3];
    const float* b_hh    = (const float*)d_in[4];
    const float* dense_w = (const float*)d_in[5];
    const float* dense_b = (const float*)d_in[6];
    float* out = (float*)d_out;

    // ws layout: h0[4096] f32 | h1[4096] f32 | ctr[64] u32 | obf bf16[H*H] (32MB)
    float*    h0  = (float*)d_ws;
    float*    h1  = h0 + HID;
    unsigned* ctr = (unsigned*)(h1 + HID);
    unsigned short* obf = (unsigned short*)(ctr + 64);

    // Zero h0|h1|ctr (contiguous 2*HID + 64 dwords; harness poisons ws).
    int nz = 2 * HID + 64;
    init_ws_kernel<<<(nz + 1023) / 1024, 1024, 0, stream>>>((unsigned*)d_ws, nz);

    size_t need = (size_t)(2 * HID + 64) * 4 + (size_t)HID * HID * sizeof(unsigned short);
    bool strb = ws_size >= need;

    static int smem_attr_set = 0;
    if (!smem_attr_set) {
        hipFuncSetAttribute((void*)lstm_kernel<true>,
                            hipFuncAttributeMaxDynamicSharedMemorySize, 160 * 1024);
        hipFuncSetAttribute((void*)lstm_kernel<false>,
                            hipFuncAttributeMaxDynamicSharedMemorySize, 160 * 1024);
        smem_attr_set = 1;
    }

    if (strb) {
        // convert gate-o rows (3H..4H) to bf16 once
        int n8 = HID * HID / 8;
        convert_o_kernel<<<2048, 256, 0, stream>>>(
            (const float4*)(w_hh + (size_t)3 * HID * HID), (uint4*)obf, n8);
        void* args[] = {(void*)&x, (void*)&w_ih, (void*)&b_ih, (void*)&b_hh,
                        (void*)&w_hh, (void*)&obf, (void*)&dense_w, (void*)&dense_b,
                        (void*)&h0, (void*)&h1, (void*)&ctr, (void*)&out};
        hipLaunchCooperativeKernel((void*)lstm_kernel<true>, dim3(NBLK), dim3(1024),
                                   args, 160 * 1024, stream);
    } else {
        void* args[] = {(void*)&x, (void*)&w_ih, (void*)&b_ih, (void*)&b_hh,
                        (void*)&w_hh, (void*)&obf, (void*)&dense_w, (void*)&dense_b,
                        (void*)&h0, (void*)&h1, (void*)&ctr, (void*)&out};
        hipLaunchCooperativeKernel((void*)lstm_kernel<false>, dim3(NBLK), dim3(1024),
                                   args, 160 * 1024, stream);
    }
}